// Round 13
// baseline (124.545 us; speedup 1.0000x reference)
//
#include <hip/hip_runtime.h>
#include <stdint.h>

#define B_    16
#define CIN_  128
#define COUT_ 128
#define H_    64
#define W_    64
#define L_    4096
#define KK_   1152

typedef unsigned short u16;
typedef __bf16 bf16x8 __attribute__((ext_vector_type(8)));
typedef float  floatx4 __attribute__((ext_vector_type(4)));
typedef uint32_t u32x4 __attribute__((ext_vector_type(4)));

typedef const __attribute__((address_space(1))) uint32_t* gptr_t;
typedef __attribute__((address_space(3))) uint32_t*       lptr_t;

__device__ __forceinline__ void async_copy16(const void* g, void* l) {
    // stages 64 lanes x 16 B = 1024 B; LDS dest = wave-uniform base + lane*16
    __builtin_amdgcn_global_load_lds((gptr_t)g, (lptr_t)l, 16, 0, 0);
}

__device__ __forceinline__ u16 f2bf(float f) {
    uint32_t u = __builtin_bit_cast(uint32_t, f);
    uint32_t r = u + 0x7FFFu + ((u >> 16) & 1u);   // round-to-nearest-even
    return (u16)(r >> 16);
}

// ---------------------------------------------------------------------------
// Prep: blocks 0..127  -> mb[o][l] = bias[o] + sum_k mw[o][k]*mask[k][l]
//       blocks 128..191 -> wb2[k][o][c] = bf16(weight[o][c][k])
// ---------------------------------------------------------------------------
__global__ void lmc_prep_kernel(const float* __restrict__ mask, const float* __restrict__ mw,
                                const float* __restrict__ bias, const float* __restrict__ w,
                                float* __restrict__ mb, u16* __restrict__ wb2) {
    const int bid = blockIdx.x, tid = threadIdx.x;
    if (bid < 128) {
        const int o = bid;
        float m[9];
        #pragma unroll
        for (int k = 0; k < 9; ++k) m[k] = mw[o * 9 + k];
        const float bs = bias[o];
        for (int l = tid; l < L_; l += 256) {
            float s = bs;
            #pragma unroll
            for (int k = 0; k < 9; ++k) s += m[k] * mask[k * L_ + l];
            mb[o * L_ + l] = s;
        }
    } else {
        const int base = (bid - 128) * 2304;
        #pragma unroll
        for (int i = 0; i < 9; ++i) {
            const int e = base + i * 256 + tid;        // 0..147455 exact
            const int k = e >> 14;                     // /16384
            const int rem = e & 16383;
            const int o = rem >> 7, c = rem & 127;
            wb2[e] = f2bf(w[(size_t)o * KK_ + c * 9 + k]);
        }
    }
}

// ---------------------------------------------------------------------------
// GEMM with the 8-PHASE-STYLE INTERLEAVE (T3+T4 port) — the one structural
// axis R5-R12 never tried. All prior variants were the "2-phase" pattern
// {stage, barrier, read+compute coupled, barrier} whose measured structural
// stall is ~70% (m233). Here each of 36 phases (tap x ks-slice) is:
//   [ks==0: issue A(tap+1) staging]  [issue ds_reads for slice g+1 -> regs]
//   [ks==2: s_waitcnt vmcnt(0) — own staging, issued 2 phases ago -> free]
//   s_barrier ; s_waitcnt lgkmcnt(0) ; sched_barrier(0)
//   setprio(1) ; mask-AND + 16 MFMA on slice g regs ; setprio(0) ; s_barrier
// Reads for g+1 issue BEFORE the barrier -> their latency lands during the
// barrier sync while other waves MFMA, not in front of the MFMAs.
// Register double-buffer S0/S1 via manual 2-unroll (all indices literal).
// Geometry = R12 (proven): LDS 163,840 B (window 6x64x128 = 98,304 +
// A full-tap dbuf 2x32,768), 256 blocks x 512 thr (8 waves 64x64, 2m x 4n),
// XCD-chunked swizzle, x-halo folded into mask bits, in-block transpose.
// ---------------------------------------------------------------------------
#define PHASE(CUR, NXT, kk, ks)                                                \
    do {                                                                       \
        if ((ks) == 0 && (kk) < 8) {                                           \
            const int koff_ = ((kk) + 1) * 32768;                              \
            char* dstb_ = A_c + (((kk) + 1) & 1) * 32768;                      \
            _Pragma("unroll")                                                  \
            for (int ti = 0; ti < 4; ++ti)                                     \
                async_copy16(wb2_c + koff_ + aoff[ti],                         \
                             dstb_ + (wv * 4 + ti) * 1024);                    \
        }                                                                      \
        if ((kk) * 4 + (ks) < 35) {                                            \
            const int kn_  = ((ks) < 3) ? (kk) : (kk) + 1;                     \
            const int ksn_ = ((ks) < 3) ? (ks) + 1 : 0;                        \
            const u16* An_ = (const u16*)(A_c + (kn_ & 1) * 32768);            \
            const int shn_ = (kn_ / 3 - 1) * 64 + (kn_ % 3) - 1;               \
            _Pragma("unroll")                                                  \
            for (int i = 0; i < 4; ++i) {                                      \
                const int orow = wm + i * 16 + lrow;                           \
                const int slot = (ksn_ * 4 + quad) ^ (orow & 7);               \
                NXT##a[i] = *reinterpret_cast<const bf16x8*>(                  \
                    &An_[orow * 128 + slot * 8]);                              \
            }                                                                  \
            _Pragma("unroll")                                                  \
            for (int j = 0; j < 4; ++j) {                                      \
                int p = pix0[j] + shn_;                                        \
                p = (p < 0) ? 0 : (p > 383 ? 383 : p);                         \
                const int slot = (ksn_ * 4 + quad) ^ (p & 7);                  \
                NXT##b[j] = *reinterpret_cast<const bf16x8*>(                  \
                    &W_lds[p * 128 + slot * 8]);                               \
            }                                                                  \
        }                                                                      \
        if ((ks) == 2)                                                         \
            asm volatile("s_waitcnt vmcnt(0)" ::: "memory");                   \
        __builtin_amdgcn_s_barrier();                                          \
        asm volatile("s_waitcnt lgkmcnt(0)" ::: "memory");                     \
        __builtin_amdgcn_sched_barrier(0);                                     \
        {                                                                      \
            bf16x8 bm[4];                                                      \
            _Pragma("unroll")                                                  \
            for (int j = 0; j < 4; ++j) {                                      \
                u32x4 t = __builtin_bit_cast(u32x4, CUR##b[j]);                \
                t &= (0u - (uint32_t)((bits >> ((kk) * 4 + j)) & 1ull));       \
                bm[j] = __builtin_bit_cast(bf16x8, t);                         \
            }                                                                  \
            __builtin_amdgcn_s_setprio(1);                                     \
            _Pragma("unroll")                                                  \
            for (int i = 0; i < 4; ++i)                                        \
                _Pragma("unroll")                                              \
                for (int j = 0; j < 4; ++j)                                    \
                    acc[i][j] = __builtin_amdgcn_mfma_f32_16x16x32_bf16(       \
                        CUR##a[i], bm[j], acc[i][j], 0, 0, 0);                 \
            __builtin_amdgcn_s_setprio(0);                                     \
        }                                                                      \
        __builtin_amdgcn_s_barrier();                                          \
    } while (0)

__global__ __launch_bounds__(512, 2)
void lmc_gemm_kernel(const float* __restrict__ x, const u16* __restrict__ wb2,
                     const float* __restrict__ mask, const float* __restrict__ mb,
                     float* __restrict__ out) {
    __shared__ u16 W_lds[384 * 128];      // 98,304 B window [pix][c], XOR-8 chunk swizzle
    __shared__ u16 A_lds[2][128 * 128];   // 2 x 32,768 B full-tap A [o][c], XOR-8

    // XCD-chunked bijective swizzle (256 blocks, 8 XCDs): XCD X gets logical
    // [32X, 32X+32) = 2 whole batches -> x working set L2-friendly per XCD.
    const int flat    = blockIdx.x;                  // 0..255
    const int logical = (flat & 7) * 32 + (flat >> 3);
    const int b       = logical >> 4;
    const int lt      = logical & 15;
    const int Y       = lt * 4;                      // first image row of tile
    const int l0      = lt * 256;

    const int tid  = threadIdx.x;
    const int lane = tid & 63;
    const int wv   = tid >> 6;                       // 0..7
    const int wm   = (wv >> 2) * 64;                 // o offset {0,64}
    const int wn   = (wv & 3) * 64;                  // l offset {0,64,128,192}
    const int lrow = lane & 15;
    const int quad = lane >> 4;

    // =======================================================================
    // Phase T: build window (image rows Y-1..Y+4, cols 0..63 only) from x.
    // Wave wv owns c-group [16wv, 16wv+16); per lane 4 c-rows x 4 x-cols.
    // =======================================================================
    {
        const int cg    = lane >> 4;                 // 0..3 (c-quad in 16)
        const int x0    = (lane & 15) * 4;
        const int cbase = wv * 16 + cg * 4;
        const int d     = wv * 2 + (cg >> 1);        // data chunk index (c>>3)
        const int half8 = (cg & 1) * 8;              // byte offset in chunk
        const float* xc = x + ((size_t)(b * CIN_ + cbase) * L_) + x0;

        #pragma unroll
        for (int wy = 0; wy < 6; ++wy) {
            const int y   = Y - 1 + wy;
            const int px0 = wy * 64 + x0;
            if (y >= 0 && y <= 63) {
                const float* xr = xc + y * 64;
                float4 v0 = *reinterpret_cast<const float4*>(xr);
                float4 v1 = *reinterpret_cast<const float4*>(xr + L_);
                float4 v2 = *reinterpret_cast<const float4*>(xr + 2 * L_);
                float4 v3 = *reinterpret_cast<const float4*>(xr + 3 * L_);
                const float* p0 = (const float*)&v0;
                const float* p1 = (const float*)&v1;
                const float* p2 = (const float*)&v2;
                const float* p3 = (const float*)&v3;
                #pragma unroll
                for (int j = 0; j < 4; ++j) {
                    const int px   = px0 + j;
                    const int slot = d ^ (px & 7);
                    uint2 pk;
                    pk.x = (uint32_t)f2bf(p0[j]) | ((uint32_t)f2bf(p1[j]) << 16);
                    pk.y = (uint32_t)f2bf(p2[j]) | ((uint32_t)f2bf(p3[j]) << 16);
                    *reinterpret_cast<uint2*>((char*)W_lds + px * 256 + slot * 16 + half8) = pk;
                }
            } else {
                const uint2 z2 = {0u, 0u};
                #pragma unroll
                for (int j = 0; j < 4; ++j) {
                    const int px   = px0 + j;
                    const int slot = d ^ (px & 7);
                    *reinterpret_cast<uint2*>((char*)W_lds + px * 256 + slot * 16 + half8) = z2;
                }
            }
        }
    }

    // ---- A staging geometry: 4 instrs/wave/tap (32 KB / 8 waves / 1 KB) ----
    // LDS A row o (256 B = 16 chunks): slot s holds source chunk s^(o&7).
    const char* wb2_c = (const char*)wb2;
    char* A_c = (char*)A_lds;
    uint32_t aoff[4];
    #pragma unroll
    for (int ti = 0; ti < 4; ++ti) {
        const int r  = 16 * wv + 4 * ti + (lane >> 4);
        const int sc = (lane & 15) ^ (r & 7);
        aoff[ti] = (uint32_t)(r * 256 + sc * 16);
    }
    // stage A(0) -> buffer 0
    #pragma unroll
    for (int ti = 0; ti < 4; ++ti)
        async_copy16(wb2_c + aoff[ti], A_c + (wv * 4 + ti) * 1024);

    // ---- per-lane window pixel bases + mask bits (mask AND x-in-bounds) ----
    int pix0[4];
    uint64_t bits = 0;
    #pragma unroll
    for (int j = 0; j < 4; ++j) {
        const int ll = wn + j * 16 + lrow;           // block-local l 0..255
        const int xx = ll & 63;
        pix0[j] = ((ll >> 6) + 1) * 64 + xx;
        const int lg = l0 + ll;
        #pragma unroll
        for (int k = 0; k < 9; ++k) {
            const int dx  = k % 3 - 1;
            const bool ok = (xx + dx >= 0) && (xx + dx < 64) &&
                            (mask[k * L_ + lg] != 0.0f);
            if (ok) bits |= (1ull << (k * 4 + j));
        }
    }

    floatx4 acc[4][4];
    #pragma unroll
    for (int i = 0; i < 4; ++i)
        #pragma unroll
        for (int j = 0; j < 4; ++j)
            acc[i][j] = (floatx4){0.f, 0.f, 0.f, 0.f};

    // phase-T ds_writes + A(0) staging complete, then publish
    asm volatile("s_waitcnt vmcnt(0) lgkmcnt(0)" ::: "memory");
    __builtin_amdgcn_s_barrier();
    asm volatile("" ::: "memory");

    // ---- prologue: read slice (tap 0, ks 0) into S0 ----
    bf16x8 S0a[4], S0b[4], S1a[4], S1b[4];
    {
        const u16* A0 = (const u16*)A_c;
        #pragma unroll
        for (int i = 0; i < 4; ++i) {
            const int orow = wm + i * 16 + lrow;
            const int slot = quad ^ (orow & 7);
            S0a[i] = *reinterpret_cast<const bf16x8*>(&A0[orow * 128 + slot * 8]);
        }
        const int sh0 = -65;                         // tap 0: dy=-1,dx=-1
        #pragma unroll
        for (int j = 0; j < 4; ++j) {
            int p = pix0[j] + sh0;
            p = (p < 0) ? 0 : p;
            const int slot = quad ^ (p & 7);
            S0b[j] = *reinterpret_cast<const bf16x8*>(&W_lds[p * 128 + slot * 8]);
        }
    }

    // ---- main loop: 36 fine-interleaved phases (9 taps x 4 ks-slices) ----
    for (int k = 0; k < 9; ++k) {
        PHASE(S0, S1, k, 0);
        PHASE(S1, S0, k, 1);
        PHASE(S0, S1, k, 2);
        PHASE(S1, S0, k, 3);
    }

    // ---- epilogue: C/D layout col = lane&15 (l), row = quad*4 + r (o) ----
    #pragma unroll
    for (int i = 0; i < 4; ++i) {
        #pragma unroll
        for (int j = 0; j < 4; ++j) {
            const int l = l0 + wn + j * 16 + lrow;
            #pragma unroll
            for (int r = 0; r < 4; ++r) {
                const int o = wm + i * 16 + quad * 4 + r;
                out[((size_t)b * COUT_ + o) * L_ + l] = acc[i][j][r] + mb[o * L_ + l];
            }
        }
    }
}

// ---------------------------------------------------------------------------
extern "C" void kernel_launch(void* const* d_in, const int* in_sizes, int n_in,
                              void* d_out, int out_size, void* d_ws, size_t ws_size,
                              hipStream_t stream) {
    const float* x      = (const float*)d_in[0];
    const float* mask   = (const float*)d_in[1];
    const float* weight = (const float*)d_in[2];
    const float* mw     = (const float*)d_in[3];
    const float* bias   = (const float*)d_in[4];
    float* out = (float*)d_out;

    char* ws = (char*)d_ws;
    u16*   wb2 = (u16*)ws;                      // 294,912 B  [9][128][128] bf16
    float* mb  = (float*)(ws + 294912);         // 2,097,152 B [128][4096] f32

    lmc_prep_kernel<<<192, 256, 0, stream>>>(mask, mw, bias, weight, mb, wb2);
    lmc_gemm_kernel<<<256, 512, 0, stream>>>(x, wb2, mask, mb, out);
}